// Round 8
// baseline (197.465 us; speedup 1.0000x reference)
//
#include <hip/hip_runtime.h>
#include <hip/hip_bf16.h>

// CompanyOperationEvaluation R8: 4 launches, gather hidden under cf_chain.
//  K1 prep_T: weight transposes only (305 blocks, ~1-2 us). Must precede K2
//             (cf_chain reads wfT/wuT) — separate launch, not a same-grid race.
//  K2 merged: blocks [0,512) = cf_chain 32-row tiles (R7-proven);
//             blocks [512,2560) = gather+cross, 8 rows/block.
//             Different blocks, same launch: gather latency (short blocks,
//             huge TLP) hides under cf_chain's HBM-bound feature read.
//             (R6 lesson refined: gather+MFMA must not share a BLOCK;
//              sharing a LAUNCH via disjoint block ranges is fine.)
//  K3 gemm128: x0 = relu(high @ W0 + b0), proven 128x128 tile.
//  K4 w1_final: 256 blocks x 64 rows full-N, x1 aliased into b_sh,
//             fused W2 GEMV + softmax + target.

typedef __bf16 bf16x8 __attribute__((ext_vector_type(8)));
typedef float floatx4 __attribute__((ext_vector_type(4)));

__device__ __forceinline__ unsigned short f2bf(float x) {
  unsigned int u = __builtin_bit_cast(unsigned int, x);
  u = (u + 0x7FFFu + ((u >> 16) & 1u)) >> 16;
  return (unsigned short)u;
}

// ---------------------------------------------------------------------------
// K1 prep_T: 32x32 transpose tiles fp32(KxN) -> bf16(NxK); block 304 = W2.
// ---------------------------------------------------------------------------
__global__ __launch_bounds__(256) void prep_kernel(
    const float* __restrict__ Wf, const float* __restrict__ Wu,
    const float* __restrict__ W0, const float* __restrict__ W1,
    const float* __restrict__ W2,
    unsigned short* __restrict__ wfT, unsigned short* __restrict__ wuT,
    unsigned short* __restrict__ w0T, unsigned short* __restrict__ w1T,
    unsigned short* __restrict__ w2T) {
  __shared__ unsigned short tile[32][34];
  const int bid = blockIdx.x, tid = threadIdx.x;
  if (bid < 304) {
    int t = bid;
    const float* src; unsigned short* dst; int N, K, kt, nt;
    if (t < 32)       { src = Wf; dst = wfT; N = 128; K = 256; kt = t >> 2;       nt = t & 3; }
    else if (t < 48)  { t -= 32;  src = Wu; dst = wuT; N = 128; K = 128; kt = t >> 2; nt = t & 3; }
    else if (t < 176) { t -= 48;  src = W0; dst = w0T; N = 512; K = 256; kt = t >> 4; nt = t & 15; }
    else              { t -= 176; src = W1; dst = w1T; N = 256; K = 512; kt = t >> 3; nt = t & 7; }
    {
      int r = tid >> 3, cg = (tid & 7) * 4;
      float4 v = *(const float4*)(src + (size_t)(kt * 32 + r) * N + nt * 32 + cg);
      tile[r][cg + 0] = f2bf(v.x); tile[r][cg + 1] = f2bf(v.y);
      tile[r][cg + 2] = f2bf(v.z); tile[r][cg + 3] = f2bf(v.w);
    }
    __syncthreads();
    {
      int rp = tid >> 3, cg = (tid & 7) * 4;
      uint2 o;
      o.x = (unsigned)tile[cg + 0][rp] | ((unsigned)tile[cg + 1][rp] << 16);
      o.y = (unsigned)tile[cg + 2][rp] | ((unsigned)tile[cg + 3][rp] << 16);
      *(uint2*)(dst + (size_t)(nt * 32 + rp) * K + kt * 32 + cg) = o;
    }
  } else {
#pragma unroll
    for (int i = 0; i < 8; ++i) {
      int g = tid * 8 + i, k = g >> 3, n = g & 7;
      w2T[n * 256 + k] = f2bf(W2[g]);
    }
  }
}

// ---------------------------------------------------------------------------
// cf_chain layer: B (128 n-rows x BK=64) staged into pad-72 LDS; wave covers
// 32 rows x 32-col strip (acc[2][2]).
// ---------------------------------------------------------------------------
template <int LDA>
__device__ __forceinline__ void layer32(const unsigned short* A_sh,
                                        const unsigned short* __restrict__ BT,
                                        int K, unsigned short* b_sh,
                                        floatx4 acc[2][2]) {
  const int tid = threadIdx.x, lane = tid & 63, wave = tid >> 6;
  const int m16 = lane & 15, quad = lane >> 4;
#pragma unroll
  for (int mi = 0; mi < 2; ++mi)
#pragma unroll
    for (int ni = 0; ni < 2; ++ni) acc[mi][ni] = (floatx4){0.f, 0.f, 0.f, 0.f};
  for (int k0 = 0; k0 < K; k0 += 64) {
    __syncthreads();  // prev b_sh reads done; producer LDS writes visible
#pragma unroll
    for (int i = 0; i < 4; ++i) {
      int chunk = i * 256 + tid;
      int row = chunk >> 3, seg = chunk & 7;
      *(uint4*)&b_sh[row * 72 + seg * 8] =
          *(const uint4*)(BT + (size_t)row * K + k0 + seg * 8);
    }
    __syncthreads();
#pragma unroll
    for (int kk = 0; kk < 64; kk += 32) {
      bf16x8 a[2], b[2];
#pragma unroll
      for (int mi = 0; mi < 2; ++mi)
        a[mi] = *(const bf16x8*)&A_sh[(mi * 16 + m16) * LDA + k0 + kk + quad * 8];
#pragma unroll
      for (int ni = 0; ni < 2; ++ni)
        b[ni] = *(const bf16x8*)&b_sh[(wave * 32 + ni * 16 + m16) * 72 + kk + quad * 8];
#pragma unroll
      for (int mi = 0; mi < 2; ++mi)
#pragma unroll
        for (int ni = 0; ni < 2; ++ni)
          acc[mi][ni] = __builtin_amdgcn_mfma_f32_16x16x32_bf16(a[mi], b[ni], acc[mi][ni], 0, 0, 0);
    }
  }
  __syncthreads();
}

// ---------------------------------------------------------------------------
// K2 merged: [0,512) cf_chain (32 rows/block); [512,2560) gather+cross.
// ---------------------------------------------------------------------------
__global__ __launch_bounds__(256) void merged_kernel(
    const float* __restrict__ features, const int* __restrict__ ent_idx,
    const float* __restrict__ head_tab, const float* __restrict__ ent_tab,
    const float* __restrict__ w_cf, const float* __restrict__ w_fc,
    const float* __restrict__ w_ef, const float* __restrict__ w_fe,
    const float* __restrict__ b_c, const float* __restrict__ b_e,
    const unsigned short* __restrict__ wfT, const unsigned short* __restrict__ wuT,
    const float* __restrict__ bf_, const float* __restrict__ bu,
    unsigned short* __restrict__ high) {
  __shared__ __align__(16) unsigned short feat_sh[32 * 264];  // 16.9 KB
  __shared__ __align__(16) unsigned short buf0[32 * 136];     //  8.7 KB
  __shared__ __align__(16) unsigned short buf1[32 * 136];     //  8.7 KB
  __shared__ __align__(16) unsigned short b_sh[128 * 72];     // 18.4 KB
  const int bid = blockIdx.x, tid = threadIdx.x;

  if (bid >= 512) {
    // ---- gather + cross_compress x2 (fp32, in-register), 8 rows/block ----
    const int row = (bid - 512) * 8 + (tid >> 5);
    const int c = (tid & 31) * 4;
    const int idx = ent_idx[row];
    float4 hv = *(const float4*)(head_tab + (size_t)idx * 128 + c);
    float4 ev = *(const float4*)(ent_tab + (size_t)idx * 128 + c);
    float h[4] = {hv.x, hv.y, hv.z, hv.w};
    float e[4] = {ev.x, ev.y, ev.z, ev.w};
    float wcf[4], wfc[4], wef[4], wfe[4];
#pragma unroll
    for (int j = 0; j < 4; ++j) {
      wcf[j] = w_cf[c + j]; wfc[j] = w_fc[c + j];
      wef[j] = w_ef[c + j]; wfe[j] = w_fe[c + j];
    }
    const float bc = b_c[0], be = b_e[0];
#pragma unroll
    for (int it = 0; it < 2; ++it) {
      float d0 = 0, d1 = 0, d2 = 0, d3 = 0;
#pragma unroll
      for (int j = 0; j < 4; ++j) {
        d0 += e[j] * wcf[j]; d1 += h[j] * wfc[j];
        d2 += e[j] * wef[j]; d3 += h[j] * wfe[j];
      }
#pragma unroll
      for (int s = 1; s < 32; s <<= 1) {
        d0 += __shfl_xor(d0, s); d1 += __shfl_xor(d1, s);
        d2 += __shfl_xor(d2, s); d3 += __shfl_xor(d3, s);
      }
      float nh[4], ne[4];
#pragma unroll
      for (int j = 0; j < 4; ++j) {
        nh[j] = h[j] * d0 + e[j] * d1 + bc;
        ne[j] = h[j] * d2 + e[j] * d3 + be;
      }
#pragma unroll
      for (int j = 0; j < 4; ++j) { h[j] = nh[j]; e[j] = ne[j]; }
    }
    uint2 v;
    v.x = (unsigned)f2bf(e[0]) | ((unsigned)f2bf(e[1]) << 16);
    v.y = (unsigned)f2bf(e[2]) | ((unsigned)f2bf(e[3]) << 16);
    *(uint2*)(high + (size_t)row * 256 + 128 + c) = v;
    return;
  }

  // ---- cf_chain: 32 rows/block ----
  const int r0 = bid * 32;
#pragma unroll
  for (int i = 0; i < 8; ++i) {
    int idx4 = i * 256 + tid;
    int row = idx4 >> 6, c = (idx4 & 63) * 4;
    float4 v = *(const float4*)(features + (size_t)(r0 + row) * 256 + c);
    uint2 o;
    o.x = (unsigned)f2bf(v.x) | ((unsigned)f2bf(v.y) << 16);
    o.y = (unsigned)f2bf(v.z) | ((unsigned)f2bf(v.w) << 16);
    *(uint2*)&feat_sh[row * 264 + c] = o;
  }
  const int lane = tid & 63, wave = tid >> 6;
  const int m16 = lane & 15, quad = lane >> 4;
  floatx4 acc[2][2];

  // L1: cf0 = relu(feat @ Wf + bf)
  layer32<264>(feat_sh, wfT, 256, b_sh, acc);
#pragma unroll
  for (int mi = 0; mi < 2; ++mi)
#pragma unroll
    for (int ni = 0; ni < 2; ++ni) {
      int col = wave * 32 + ni * 16 + m16;
      float bv = bf_[col];
#pragma unroll
      for (int r = 0; r < 4; ++r)
        buf0[(mi * 16 + quad * 4 + r) * 136 + col] =
            f2bf(fmaxf(acc[mi][ni][r] + bv, 0.f));
    }
  // L2: cf1 = relu(cf0 @ Wu + bu)
  layer32<136>(buf0, wuT, 128, b_sh, acc);
#pragma unroll
  for (int mi = 0; mi < 2; ++mi)
#pragma unroll
    for (int ni = 0; ni < 2; ++ni) {
      int col = wave * 32 + ni * 16 + m16;
      float bv = bu[col];
#pragma unroll
      for (int r = 0; r < 4; ++r)
        buf1[(mi * 16 + quad * 4 + r) * 136 + col] =
            f2bf(fmaxf(acc[mi][ni][r] + bv, 0.f));
    }
  // L3: cf2 = relu(cf1 @ Wu + bu) -> high[:, 0:128]
  layer32<136>(buf1, wuT, 128, b_sh, acc);
#pragma unroll
  for (int mi = 0; mi < 2; ++mi)
#pragma unroll
    for (int ni = 0; ni < 2; ++ni) {
      int col = wave * 32 + ni * 16 + m16;
      float bv = bu[col];
#pragma unroll
      for (int r = 0; r < 4; ++r) {
        int row = r0 + mi * 16 + quad * 4 + r;
        high[(size_t)row * 256 + col] = f2bf(fmaxf(acc[mi][ni][r] + bv, 0.f));
      }
    }
}

// ---------------------------------------------------------------------------
// K3 gemm128: proven 128x128 tile, BK=64, 4 waves 2x2 (64x64, acc[4][4]).
// ---------------------------------------------------------------------------
__global__ __launch_bounds__(256) void gemm128_kernel(
    const unsigned short* __restrict__ A, const unsigned short* __restrict__ BT,
    const float* __restrict__ bias, unsigned short* __restrict__ C,
    int K, int ldc) {
  __shared__ __align__(16) unsigned short a_sh[128 * 72];
  __shared__ __align__(16) unsigned short b_sh[128 * 72];
  const int tid = threadIdx.x;
  const int bn = blockIdx.x, bm = blockIdx.y;
  const int lane = tid & 63;
  const int wave = tid >> 6;
  const int wm = wave & 1, wn = wave >> 1;
  const int m16 = lane & 15, quad = lane >> 4;

  floatx4 acc[4][4];
#pragma unroll
  for (int i = 0; i < 4; ++i)
#pragma unroll
    for (int j = 0; j < 4; ++j) acc[i][j] = (floatx4){0.f, 0.f, 0.f, 0.f};

  for (int k0 = 0; k0 < K; k0 += 64) {
    __syncthreads();
#pragma unroll
    for (int i = 0; i < 4; ++i) {
      int chunk = i * 256 + tid;
      int row = chunk >> 3, seg = chunk & 7;
      *(uint4*)&a_sh[row * 72 + seg * 8] =
          *(const uint4*)(A + (size_t)(bm * 128 + row) * K + k0 + seg * 8);
      *(uint4*)&b_sh[row * 72 + seg * 8] =
          *(const uint4*)(BT + (size_t)(bn * 128 + row) * K + k0 + seg * 8);
    }
    __syncthreads();
#pragma unroll
    for (int kk = 0; kk < 64; kk += 32) {
      bf16x8 af[4], bfr[4];
#pragma unroll
      for (int mi = 0; mi < 4; ++mi)
        af[mi] = *(const bf16x8*)&a_sh[(wm * 64 + mi * 16 + m16) * 72 + kk + quad * 8];
#pragma unroll
      for (int ni = 0; ni < 4; ++ni)
        bfr[ni] = *(const bf16x8*)&b_sh[(wn * 64 + ni * 16 + m16) * 72 + kk + quad * 8];
#pragma unroll
      for (int mi = 0; mi < 4; ++mi)
#pragma unroll
        for (int ni = 0; ni < 4; ++ni)
          acc[mi][ni] = __builtin_amdgcn_mfma_f32_16x16x32_bf16(
              af[mi], bfr[ni], acc[mi][ni], 0, 0, 0);
    }
  }
#pragma unroll
  for (int mi = 0; mi < 4; ++mi) {
#pragma unroll
    for (int ni = 0; ni < 4; ++ni) {
      int col = bn * 128 + wn * 64 + ni * 16 + m16;
      float bv = bias[col];
#pragma unroll
      for (int r = 0; r < 4; ++r) {
        int row = bm * 128 + wm * 64 + mi * 16 + quad * 4 + r;
        C[(size_t)row * ldc + col] = f2bf(fmaxf(acc[mi][ni][r] + bv, 0.f));
      }
    }
  }
}

// ---------------------------------------------------------------------------
// K4 w1_final: 256 blocks x 64 rows x full N=256. LDS 50.1 KB -> 3 blocks/CU.
// Wave: 64 rows x cols wave*64, acc[4][4] (16 MFMAs / 8 reads per kk).
// x1 aliased into b_sh. Fused W2 GEMV + softmax + target.
// ---------------------------------------------------------------------------
__global__ __launch_bounds__(256) void gemm_w1_final_kernel(
    const unsigned short* __restrict__ x0, const unsigned short* __restrict__ w1T,
    const float* __restrict__ b1, const unsigned short* __restrict__ w2T,
    const float* __restrict__ b2, const int* __restrict__ target,
    float* __restrict__ out) {
  __shared__ __align__(16) unsigned short a_sh[64 * 72];    //  9.2 KB
  __shared__ __align__(16) unsigned short b_sh[256 * 72];   // 36.9 KB
  __shared__ __align__(16) unsigned short w2_sh[2048];      //  4.0 KB
  unsigned short* x1_sh = b_sh;  // x1 tile 64x264 = 33.8 KB <= b_sh
  const int tid = threadIdx.x;
  const int r0 = blockIdx.x * 64;
  *(uint4*)&w2_sh[tid * 8] = *(const uint4*)(w2T + tid * 8);
  const int lane = tid & 63, wave = tid >> 6;
  const int m16 = lane & 15, quad = lane >> 4;
  floatx4 acc[4][4];
#pragma unroll
  for (int mi = 0; mi < 4; ++mi)
#pragma unroll
    for (int ni = 0; ni < 4; ++ni) acc[mi][ni] = (floatx4){0.f, 0.f, 0.f, 0.f};

  for (int k0 = 0; k0 < 512; k0 += 64) {
    __syncthreads();
#pragma unroll
    for (int i = 0; i < 2; ++i) {
      int chunk = i * 256 + tid;
      int row = chunk >> 3, seg = chunk & 7;
      *(uint4*)&a_sh[row * 72 + seg * 8] =
          *(const uint4*)(x0 + (size_t)(r0 + row) * 512 + k0 + seg * 8);
    }
#pragma unroll
    for (int i = 0; i < 8; ++i) {
      int chunk = i * 256 + tid;
      int row = chunk >> 3, seg = chunk & 7;
      *(uint4*)&b_sh[row * 72 + seg * 8] =
          *(const uint4*)(w1T + (size_t)row * 512 + k0 + seg * 8);
    }
    __syncthreads();
#pragma unroll
    for (int kk = 0; kk < 64; kk += 32) {
      bf16x8 a[4], b[4];
#pragma unroll
      for (int mi = 0; mi < 4; ++mi)
        a[mi] = *(const bf16x8*)&a_sh[(mi * 16 + m16) * 72 + kk + quad * 8];
#pragma unroll
      for (int ni = 0; ni < 4; ++ni)
        b[ni] = *(const bf16x8*)&b_sh[(wave * 64 + ni * 16 + m16) * 72 + kk + quad * 8];
#pragma unroll
      for (int mi = 0; mi < 4; ++mi)
#pragma unroll
        for (int ni = 0; ni < 4; ++ni)
          acc[mi][ni] = __builtin_amdgcn_mfma_f32_16x16x32_bf16(a[mi], b[ni], acc[mi][ni], 0, 0, 0);
    }
  }
  __syncthreads();  // all b_sh MFMA reads done before aliased x1 writes
#pragma unroll
  for (int mi = 0; mi < 4; ++mi)
#pragma unroll
    for (int ni = 0; ni < 4; ++ni) {
      int col = wave * 64 + ni * 16 + m16;
      float bv = b1[col];
#pragma unroll
      for (int r = 0; r < 4; ++r)
        x1_sh[(mi * 16 + quad * 4 + r) * 264 + col] = f2bf(fmaxf(acc[mi][ni][r] + bv, 0.f));
    }
  __syncthreads();
  // W2 GEMV + softmax: 4 lanes/row, 64 elems/lane
  {
    int row = tid >> 2, q = tid & 3;
    float p[8];
#pragma unroll
    for (int n = 0; n < 8; ++n) p[n] = 0.f;
#pragma unroll
    for (int jb = 0; jb < 8; ++jb) {
      bf16x8 xv = *(const bf16x8*)&x1_sh[row * 264 + q * 64 + jb * 8];
#pragma unroll
      for (int n = 0; n < 8; ++n) {
        bf16x8 wv = *(const bf16x8*)&w2_sh[n * 256 + q * 64 + jb * 8];
#pragma unroll
        for (int j = 0; j < 8; ++j) p[n] += (float)xv[j] * (float)wv[j];
      }
    }
#pragma unroll
    for (int s = 1; s < 4; s <<= 1)
#pragma unroll
      for (int n = 0; n < 8; ++n) p[n] += __shfl_xor(p[n], s);
    if (q == 0) {
      float mx = -1e30f;
#pragma unroll
      for (int n = 0; n < 8; ++n) {
        p[n] = fmaxf(p[n] + b2[n], 0.f);
        mx = fmaxf(mx, p[n]);
      }
      float sum = 0.f;
#pragma unroll
      for (int n = 0; n < 8; ++n) { p[n] = __expf(p[n] - mx); sum += p[n]; }
      const float inv = 1.f / sum;
      const int gr = r0 + row;
      float4 o0 = {p[0] * inv, p[1] * inv, p[2] * inv, p[3] * inv};
      float4 o1 = {p[4] * inv, p[5] * inv, p[6] * inv, p[7] * inv};
      *(float4*)(out + (size_t)gr * 8) = o0;
      *(float4*)(out + (size_t)gr * 8 + 4) = o1;
      out[16384 * 8 + gr] = (float)target[gr];
    }
  }
}

extern "C" void kernel_launch(void* const* d_in, const int* in_sizes, int n_in,
                              void* d_out, int out_size, void* d_ws, size_t ws_size,
                              hipStream_t stream) {
  const float* features = (const float*)d_in[0];
  const int* ent_idx    = (const int*)d_in[1];
  const int* target     = (const int*)d_in[2];
  const float* Wf  = (const float*)d_in[3];
  const float* bf_ = (const float*)d_in[4];
  const float* Wu  = (const float*)d_in[5];
  const float* bu  = (const float*)d_in[6];
  const float* w_cf = (const float*)d_in[7];
  const float* w_fc = (const float*)d_in[8];
  const float* w_ef = (const float*)d_in[9];
  const float* w_fe = (const float*)d_in[10];
  const float* b_c  = (const float*)d_in[11];
  const float* b_e  = (const float*)d_in[12];
  const float* head_tab = (const float*)d_in[13];
  const float* ent_tab  = (const float*)d_in[14];
  const float* W0 = (const float*)d_in[15];
  const float* b0 = (const float*)d_in[16];
  const float* W1 = (const float*)d_in[17];
  const float* b1 = (const float*)d_in[18];
  const float* W2 = (const float*)d_in[19];
  const float* b2 = (const float*)d_in[20];
  float* out = (float*)d_out;

  unsigned short* ws = (unsigned short*)d_ws;
  size_t off = 0;
  auto alloc = [&](size_t n) { unsigned short* p = ws + off; off += n; return p; };
  unsigned short* high = alloc(16384ull * 256);
  unsigned short* x0   = alloc(16384ull * 512);
  unsigned short* wfT  = alloc(32768);
  unsigned short* wuT  = alloc(16384);
  unsigned short* w0T  = alloc(131072);
  unsigned short* w1T  = alloc(131072);
  unsigned short* w2T  = alloc(2048);
  (void)ws_size; (void)in_sizes; (void)n_in; (void)out_size;

  // K1: weight transposes (must precede K2's cf_chain reads of wfT/wuT)
  prep_kernel<<<305, 256, 0, stream>>>(Wf, Wu, W0, W1, W2,
                                       wfT, wuT, w0T, w1T, w2T);
  // K2: cf_chain blocks [0,512) + gather blocks [512,2560) -> full high
  merged_kernel<<<2560, 256, 0, stream>>>(features, ent_idx, head_tab,
      ent_tab, w_cf, w_fc, w_ef, w_fe, b_c, b_e, wfT, wuT, bf_, bu, high);
  // K3: x0 = relu(high @ W0 + b0), 128x128 tiles
  gemm128_kernel<<<dim3(4, 128), 256, 0, stream>>>(high, w0T, b0, x0, 256, 512);
  // K4: x1 GEMM + W2 + softmax + target
  gemm_w1_final_kernel<<<256, 256, 0, stream>>>(x0, w1T, b1, w2T, b2, target, out);
}

// Round 9
// 188.923 us; speedup vs baseline: 1.0452x; 1.0452x over previous
//
#include <hip/hip_runtime.h>
#include <hip/hip_bf16.h>

// CompanyOperationEvaluation R9 = R4 exact revert (best measured, 191.6 us).
//  K1 prep: gather+cross (2048 blocks, tiny LDS -> max TLP for random row
//           fetches) + weight transposes (304 blocks) + W2 (1 block).
//  K2 cf_chain: 512 blocks x 32 rows (3 blocks/CU), feat->cf0->cf1->cf2.
//  K3 gemm128: x0 = relu(high @ W0 + b0), proven 128x128 tile.
//  K4 w1_final: 512 blocks x 32 rows full-N, x1 aliased into b_sh,
//           fused W2 GEMV + softmax + target.
// Lesson bank: (R2) never feed MFMA operands from global at low occupancy;
// (R5) don't shrink M-tile-per-barrier below ~8 MFMAs/wave/chunk;
// (R6) random-gather and MFMA phases must not share a block;
// (R8) block-range fusion inherits max LDS across branches — don't co-launch
// LDS-heavy MFMA blocks with occupancy-hungry gather blocks.

typedef __bf16 bf16x8 __attribute__((ext_vector_type(8)));
typedef float floatx4 __attribute__((ext_vector_type(4)));

__device__ __forceinline__ unsigned short f2bf(float x) {
  unsigned int u = __builtin_bit_cast(unsigned int, x);
  u = (u + 0x7FFFu + ((u >> 16) & 1u)) >> 16;
  return (unsigned short)u;
}

// ---------------------------------------------------------------------------
// K1 prep: blocks [0,2048) gather+cross (8 rows/block, 32 lanes/row);
// blocks [2048,2352) 32x32 transpose tiles; block 2352 W2.
// ---------------------------------------------------------------------------
__global__ __launch_bounds__(256) void prep_kernel(
    const int* __restrict__ ent_idx, const float* __restrict__ head_tab,
    const float* __restrict__ ent_tab,
    const float* __restrict__ w_cf, const float* __restrict__ w_fc,
    const float* __restrict__ w_ef, const float* __restrict__ w_fe,
    const float* __restrict__ b_c, const float* __restrict__ b_e,
    const float* __restrict__ Wf, const float* __restrict__ Wu,
    const float* __restrict__ W0, const float* __restrict__ W1,
    const float* __restrict__ W2,
    unsigned short* __restrict__ high,
    unsigned short* __restrict__ wfT, unsigned short* __restrict__ wuT,
    unsigned short* __restrict__ w0T, unsigned short* __restrict__ w1T,
    unsigned short* __restrict__ w2T) {
  __shared__ unsigned short tile[32][34];
  const int bid = blockIdx.x, tid = threadIdx.x;
  if (bid < 2048) {
    // gather + cross_compress x2 (fp32, in-register), 8 rows/block
    const int row = bid * 8 + (tid >> 5);
    const int c = (tid & 31) * 4;
    const int idx = ent_idx[row];
    float4 hv = *(const float4*)(head_tab + (size_t)idx * 128 + c);
    float4 ev = *(const float4*)(ent_tab + (size_t)idx * 128 + c);
    float h[4] = {hv.x, hv.y, hv.z, hv.w};
    float e[4] = {ev.x, ev.y, ev.z, ev.w};
    float wcf[4], wfc[4], wef[4], wfe[4];
#pragma unroll
    for (int j = 0; j < 4; ++j) {
      wcf[j] = w_cf[c + j]; wfc[j] = w_fc[c + j];
      wef[j] = w_ef[c + j]; wfe[j] = w_fe[c + j];
    }
    const float bc = b_c[0], be = b_e[0];
#pragma unroll
    for (int it = 0; it < 2; ++it) {
      float d0 = 0, d1 = 0, d2 = 0, d3 = 0;
#pragma unroll
      for (int j = 0; j < 4; ++j) {
        d0 += e[j] * wcf[j]; d1 += h[j] * wfc[j];
        d2 += e[j] * wef[j]; d3 += h[j] * wfe[j];
      }
#pragma unroll
      for (int s = 1; s < 32; s <<= 1) {
        d0 += __shfl_xor(d0, s); d1 += __shfl_xor(d1, s);
        d2 += __shfl_xor(d2, s); d3 += __shfl_xor(d3, s);
      }
      float nh[4], ne[4];
#pragma unroll
      for (int j = 0; j < 4; ++j) {
        nh[j] = h[j] * d0 + e[j] * d1 + bc;
        ne[j] = h[j] * d2 + e[j] * d3 + be;
      }
#pragma unroll
      for (int j = 0; j < 4; ++j) { h[j] = nh[j]; e[j] = ne[j]; }
    }
    uint2 v;
    v.x = (unsigned)f2bf(e[0]) | ((unsigned)f2bf(e[1]) << 16);
    v.y = (unsigned)f2bf(e[2]) | ((unsigned)f2bf(e[3]) << 16);
    *(uint2*)(high + (size_t)row * 256 + 128 + c) = v;
  } else if (bid < 2352) {
    // 32x32 transpose tiles: src (K x N) fp32 -> dst (N x K) bf16
    int t = bid - 2048;
    const float* src; unsigned short* dst; int N, K, kt, nt;
    if (t < 32)       { src = Wf; dst = wfT; N = 128; K = 256; kt = t >> 2;       nt = t & 3; }
    else if (t < 48)  { t -= 32;  src = Wu; dst = wuT; N = 128; K = 128; kt = t >> 2; nt = t & 3; }
    else if (t < 176) { t -= 48;  src = W0; dst = w0T; N = 512; K = 256; kt = t >> 4; nt = t & 15; }
    else              { t -= 176; src = W1; dst = w1T; N = 256; K = 512; kt = t >> 3; nt = t & 7; }
    {
      int r = tid >> 3, cg = (tid & 7) * 4;
      float4 v = *(const float4*)(src + (size_t)(kt * 32 + r) * N + nt * 32 + cg);
      tile[r][cg + 0] = f2bf(v.x); tile[r][cg + 1] = f2bf(v.y);
      tile[r][cg + 2] = f2bf(v.z); tile[r][cg + 3] = f2bf(v.w);
    }
    __syncthreads();
    {
      int rp = tid >> 3, cg = (tid & 7) * 4;
      uint2 o;
      o.x = (unsigned)tile[cg + 0][rp] | ((unsigned)tile[cg + 1][rp] << 16);
      o.y = (unsigned)tile[cg + 2][rp] | ((unsigned)tile[cg + 3][rp] << 16);
      *(uint2*)(dst + (size_t)(nt * 32 + rp) * K + kt * 32 + cg) = o;
    }
  } else {
    // W2 256x8 -> 8x256
#pragma unroll
    for (int i = 0; i < 8; ++i) {
      int g = tid * 8 + i, k = g >> 3, n = g & 7;
      w2T[n * 256 + k] = f2bf(W2[g]);
    }
  }
}

// ---------------------------------------------------------------------------
// K2 cf_chain: 512 blocks x 32 rows, 52.7 KB LDS -> 3 blocks/CU.
// Per layer: B (128 n-rows x BK=64) staged into pad-72 LDS; wave covers
// 32 rows x 32-col strip (acc[2][2]).
// ---------------------------------------------------------------------------
template <int LDA>
__device__ __forceinline__ void layer32(const unsigned short* A_sh,
                                        const unsigned short* __restrict__ BT,
                                        int K, unsigned short* b_sh,
                                        floatx4 acc[2][2]) {
  const int tid = threadIdx.x, lane = tid & 63, wave = tid >> 6;
  const int m16 = lane & 15, quad = lane >> 4;
#pragma unroll
  for (int mi = 0; mi < 2; ++mi)
#pragma unroll
    for (int ni = 0; ni < 2; ++ni) acc[mi][ni] = (floatx4){0.f, 0.f, 0.f, 0.f};
  for (int k0 = 0; k0 < K; k0 += 64) {
    __syncthreads();  // prev b_sh reads done; producer LDS writes visible
#pragma unroll
    for (int i = 0; i < 4; ++i) {
      int chunk = i * 256 + tid;
      int row = chunk >> 3, seg = chunk & 7;
      *(uint4*)&b_sh[row * 72 + seg * 8] =
          *(const uint4*)(BT + (size_t)row * K + k0 + seg * 8);
    }
    __syncthreads();
#pragma unroll
    for (int kk = 0; kk < 64; kk += 32) {
      bf16x8 a[2], b[2];
#pragma unroll
      for (int mi = 0; mi < 2; ++mi)
        a[mi] = *(const bf16x8*)&A_sh[(mi * 16 + m16) * LDA + k0 + kk + quad * 8];
#pragma unroll
      for (int ni = 0; ni < 2; ++ni)
        b[ni] = *(const bf16x8*)&b_sh[(wave * 32 + ni * 16 + m16) * 72 + kk + quad * 8];
#pragma unroll
      for (int mi = 0; mi < 2; ++mi)
#pragma unroll
        for (int ni = 0; ni < 2; ++ni)
          acc[mi][ni] = __builtin_amdgcn_mfma_f32_16x16x32_bf16(a[mi], b[ni], acc[mi][ni], 0, 0, 0);
    }
  }
  __syncthreads();
}

__global__ __launch_bounds__(256) void cf_chain_kernel(
    const float* __restrict__ features, const unsigned short* __restrict__ wfT,
    const unsigned short* __restrict__ wuT, const float* __restrict__ bf_,
    const float* __restrict__ bu, unsigned short* __restrict__ high) {
  __shared__ __align__(16) unsigned short feat_sh[32 * 264];  // 16.9 KB
  __shared__ __align__(16) unsigned short buf0[32 * 136];     //  8.7 KB
  __shared__ __align__(16) unsigned short buf1[32 * 136];     //  8.7 KB
  __shared__ __align__(16) unsigned short b_sh[128 * 72];     // 18.4 KB
  const int tid = threadIdx.x;
  const int r0 = blockIdx.x * 32;
  // stage features fp32->bf16: 2048 float4, 8/thread, coalesced
#pragma unroll
  for (int i = 0; i < 8; ++i) {
    int idx4 = i * 256 + tid;
    int row = idx4 >> 6, c = (idx4 & 63) * 4;
    float4 v = *(const float4*)(features + (size_t)(r0 + row) * 256 + c);
    uint2 o;
    o.x = (unsigned)f2bf(v.x) | ((unsigned)f2bf(v.y) << 16);
    o.y = (unsigned)f2bf(v.z) | ((unsigned)f2bf(v.w) << 16);
    *(uint2*)&feat_sh[row * 264 + c] = o;
  }
  const int lane = tid & 63, wave = tid >> 6;
  const int m16 = lane & 15, quad = lane >> 4;
  floatx4 acc[2][2];

  // L1: cf0 = relu(feat @ Wf + bf)
  layer32<264>(feat_sh, wfT, 256, b_sh, acc);
#pragma unroll
  for (int mi = 0; mi < 2; ++mi)
#pragma unroll
    for (int ni = 0; ni < 2; ++ni) {
      int col = wave * 32 + ni * 16 + m16;
      float bv = bf_[col];
#pragma unroll
      for (int r = 0; r < 4; ++r)
        buf0[(mi * 16 + quad * 4 + r) * 136 + col] =
            f2bf(fmaxf(acc[mi][ni][r] + bv, 0.f));
    }
  // L2: cf1 = relu(cf0 @ Wu + bu)
  layer32<136>(buf0, wuT, 128, b_sh, acc);
#pragma unroll
  for (int mi = 0; mi < 2; ++mi)
#pragma unroll
    for (int ni = 0; ni < 2; ++ni) {
      int col = wave * 32 + ni * 16 + m16;
      float bv = bu[col];
#pragma unroll
      for (int r = 0; r < 4; ++r)
        buf1[(mi * 16 + quad * 4 + r) * 136 + col] =
            f2bf(fmaxf(acc[mi][ni][r] + bv, 0.f));
    }
  // L3: cf2 = relu(cf1 @ Wu + bu) -> high[:, 0:128]
  layer32<136>(buf1, wuT, 128, b_sh, acc);
#pragma unroll
  for (int mi = 0; mi < 2; ++mi)
#pragma unroll
    for (int ni = 0; ni < 2; ++ni) {
      int col = wave * 32 + ni * 16 + m16;
      float bv = bu[col];
#pragma unroll
      for (int r = 0; r < 4; ++r) {
        int row = r0 + mi * 16 + quad * 4 + r;
        high[(size_t)row * 256 + col] = f2bf(fmaxf(acc[mi][ni][r] + bv, 0.f));
      }
    }
}

// ---------------------------------------------------------------------------
// K3 gemm128: proven 128x128 tile, BK=64, 4 waves 2x2 (64x64, acc[4][4]).
// ---------------------------------------------------------------------------
__global__ __launch_bounds__(256) void gemm128_kernel(
    const unsigned short* __restrict__ A, const unsigned short* __restrict__ BT,
    const float* __restrict__ bias, unsigned short* __restrict__ C,
    int K, int ldc) {
  __shared__ __align__(16) unsigned short a_sh[128 * 72];
  __shared__ __align__(16) unsigned short b_sh[128 * 72];
  const int tid = threadIdx.x;
  const int bn = blockIdx.x, bm = blockIdx.y;
  const int lane = tid & 63;
  const int wave = tid >> 6;
  const int wm = wave & 1, wn = wave >> 1;
  const int m16 = lane & 15, quad = lane >> 4;

  floatx4 acc[4][4];
#pragma unroll
  for (int i = 0; i < 4; ++i)
#pragma unroll
    for (int j = 0; j < 4; ++j) acc[i][j] = (floatx4){0.f, 0.f, 0.f, 0.f};

  for (int k0 = 0; k0 < K; k0 += 64) {
    __syncthreads();
#pragma unroll
    for (int i = 0; i < 4; ++i) {
      int chunk = i * 256 + tid;
      int row = chunk >> 3, seg = chunk & 7;
      *(uint4*)&a_sh[row * 72 + seg * 8] =
          *(const uint4*)(A + (size_t)(bm * 128 + row) * K + k0 + seg * 8);
      *(uint4*)&b_sh[row * 72 + seg * 8] =
          *(const uint4*)(BT + (size_t)(bn * 128 + row) * K + k0 + seg * 8);
    }
    __syncthreads();
#pragma unroll
    for (int kk = 0; kk < 64; kk += 32) {
      bf16x8 af[4], bfr[4];
#pragma unroll
      for (int mi = 0; mi < 4; ++mi)
        af[mi] = *(const bf16x8*)&a_sh[(wm * 64 + mi * 16 + m16) * 72 + kk + quad * 8];
#pragma unroll
      for (int ni = 0; ni < 4; ++ni)
        bfr[ni] = *(const bf16x8*)&b_sh[(wn * 64 + ni * 16 + m16) * 72 + kk + quad * 8];
#pragma unroll
      for (int mi = 0; mi < 4; ++mi)
#pragma unroll
        for (int ni = 0; ni < 4; ++ni)
          acc[mi][ni] = __builtin_amdgcn_mfma_f32_16x16x32_bf16(
              af[mi], bfr[ni], acc[mi][ni], 0, 0, 0);
    }
  }
#pragma unroll
  for (int mi = 0; mi < 4; ++mi) {
#pragma unroll
    for (int ni = 0; ni < 4; ++ni) {
      int col = bn * 128 + wn * 64 + ni * 16 + m16;
      float bv = bias[col];
#pragma unroll
      for (int r = 0; r < 4; ++r) {
        int row = bm * 128 + wm * 64 + mi * 16 + quad * 4 + r;
        C[(size_t)row * ldc + col] = f2bf(fmaxf(acc[mi][ni][r] + bv, 0.f));
      }
    }
  }
}

// ---------------------------------------------------------------------------
// K4 w1_final: 512 blocks x 32 rows x full N=256. LDS 45.5 KB
// (x1 tile aliased into b_sh) -> 2-3 blocks/CU. Wave: 32 rows x cols wave*64
// (acc[2][4]). Fused W2 GEMV + softmax + target epilogue.
// ---------------------------------------------------------------------------
__global__ __launch_bounds__(256) void gemm_w1_final_kernel(
    const unsigned short* __restrict__ x0, const unsigned short* __restrict__ w1T,
    const float* __restrict__ b1, const unsigned short* __restrict__ w2T,
    const float* __restrict__ b2, const int* __restrict__ target,
    float* __restrict__ out) {
  __shared__ __align__(16) unsigned short a_sh[32 * 72];    //  4.6 KB
  __shared__ __align__(16) unsigned short b_sh[256 * 72];   // 36.9 KB
  __shared__ __align__(16) unsigned short w2_sh[2048];      //  4.0 KB
  unsigned short* x1_sh = b_sh;  // aliased: x1 tile 32x264 = 16.5 KB <= b_sh
  const int tid = threadIdx.x;
  const int r0 = blockIdx.x * 32;
  *(uint4*)&w2_sh[tid * 8] = *(const uint4*)(w2T + tid * 8);
  const int lane = tid & 63, wave = tid >> 6;
  const int m16 = lane & 15, quad = lane >> 4;
  floatx4 acc[2][4];
#pragma unroll
  for (int mi = 0; mi < 2; ++mi)
#pragma unroll
    for (int ni = 0; ni < 4; ++ni) acc[mi][ni] = (floatx4){0.f, 0.f, 0.f, 0.f};

  for (int k0 = 0; k0 < 512; k0 += 64) {
    __syncthreads();
    // stage A chunk: 32 rows x 64 k (256 uint4, 1/thread)
    {
      int row = tid >> 3, seg = tid & 7;
      *(uint4*)&a_sh[row * 72 + seg * 8] =
          *(const uint4*)(x0 + (size_t)(r0 + row) * 512 + k0 + seg * 8);
    }
    // stage B chunk: 256 n-rows x 64 k (2048 uint4, 8/thread)
#pragma unroll
    for (int i = 0; i < 8; ++i) {
      int chunk = i * 256 + tid;
      int row = chunk >> 3, seg = chunk & 7;
      *(uint4*)&b_sh[row * 72 + seg * 8] =
          *(const uint4*)(w1T + (size_t)row * 512 + k0 + seg * 8);
    }
    __syncthreads();
#pragma unroll
    for (int kk = 0; kk < 64; kk += 32) {
      bf16x8 a[2], b[4];
#pragma unroll
      for (int mi = 0; mi < 2; ++mi)
        a[mi] = *(const bf16x8*)&a_sh[(mi * 16 + m16) * 72 + kk + quad * 8];
#pragma unroll
      for (int ni = 0; ni < 4; ++ni)
        b[ni] = *(const bf16x8*)&b_sh[(wave * 64 + ni * 16 + m16) * 72 + kk + quad * 8];
#pragma unroll
      for (int mi = 0; mi < 2; ++mi)
#pragma unroll
        for (int ni = 0; ni < 4; ++ni)
          acc[mi][ni] = __builtin_amdgcn_mfma_f32_16x16x32_bf16(a[mi], b[ni], acc[mi][ni], 0, 0, 0);
    }
  }
  __syncthreads();  // all b_sh MFMA reads done before aliased x1 writes
#pragma unroll
  for (int mi = 0; mi < 2; ++mi)
#pragma unroll
    for (int ni = 0; ni < 4; ++ni) {
      int col = wave * 64 + ni * 16 + m16;
      float bv = b1[col];
#pragma unroll
      for (int r = 0; r < 4; ++r)
        x1_sh[(mi * 16 + quad * 4 + r) * 264 + col] = f2bf(fmaxf(acc[mi][ni][r] + bv, 0.f));
    }
  __syncthreads();
  // W2 GEMV + softmax: 8 lanes/row, 32 elems/lane
  {
    int row = tid >> 3, q = tid & 7;
    float p[8];
#pragma unroll
    for (int n = 0; n < 8; ++n) p[n] = 0.f;
#pragma unroll
    for (int jb = 0; jb < 4; ++jb) {
      bf16x8 xv = *(const bf16x8*)&x1_sh[row * 264 + q * 32 + jb * 8];
#pragma unroll
      for (int n = 0; n < 8; ++n) {
        bf16x8 wv = *(const bf16x8*)&w2_sh[n * 256 + q * 32 + jb * 8];
#pragma unroll
        for (int j = 0; j < 8; ++j) p[n] += (float)xv[j] * (float)wv[j];
      }
    }
#pragma unroll
    for (int s = 1; s < 8; s <<= 1)
#pragma unroll
      for (int n = 0; n < 8; ++n) p[n] += __shfl_xor(p[n], s);
    if (q == 0) {
      float mx = -1e30f;
#pragma unroll
      for (int n = 0; n < 8; ++n) {
        p[n] = fmaxf(p[n] + b2[n], 0.f);
        mx = fmaxf(mx, p[n]);
      }
      float sum = 0.f;
#pragma unroll
      for (int n = 0; n < 8; ++n) { p[n] = __expf(p[n] - mx); sum += p[n]; }
      const float inv = 1.f / sum;
      const int gr = r0 + row;
      float4 o0 = {p[0] * inv, p[1] * inv, p[2] * inv, p[3] * inv};
      float4 o1 = {p[4] * inv, p[5] * inv, p[6] * inv, p[7] * inv};
      *(float4*)(out + (size_t)gr * 8) = o0;
      *(float4*)(out + (size_t)gr * 8 + 4) = o1;
      out[16384 * 8 + gr] = (float)target[gr];
    }
  }
}

extern "C" void kernel_launch(void* const* d_in, const int* in_sizes, int n_in,
                              void* d_out, int out_size, void* d_ws, size_t ws_size,
                              hipStream_t stream) {
  const float* features = (const float*)d_in[0];
  const int* ent_idx    = (const int*)d_in[1];
  const int* target     = (const int*)d_in[2];
  const float* Wf  = (const float*)d_in[3];
  const float* bf_ = (const float*)d_in[4];
  const float* Wu  = (const float*)d_in[5];
  const float* bu  = (const float*)d_in[6];
  const float* w_cf = (const float*)d_in[7];
  const float* w_fc = (const float*)d_in[8];
  const float* w_ef = (const float*)d_in[9];
  const float* w_fe = (const float*)d_in[10];
  const float* b_c  = (const float*)d_in[11];
  const float* b_e  = (const float*)d_in[12];
  const float* head_tab = (const float*)d_in[13];
  const float* ent_tab  = (const float*)d_in[14];
  const float* W0 = (const float*)d_in[15];
  const float* b0 = (const float*)d_in[16];
  const float* W1 = (const float*)d_in[17];
  const float* b1 = (const float*)d_in[18];
  const float* W2 = (const float*)d_in[19];
  const float* b2 = (const float*)d_in[20];
  float* out = (float*)d_out;

  unsigned short* ws = (unsigned short*)d_ws;
  size_t off = 0;
  auto alloc = [&](size_t n) { unsigned short* p = ws + off; off += n; return p; };
  unsigned short* high = alloc(16384ull * 256);
  unsigned short* x0   = alloc(16384ull * 512);
  unsigned short* wfT  = alloc(32768);
  unsigned short* wuT  = alloc(16384);
  unsigned short* w0T  = alloc(131072);
  unsigned short* w1T  = alloc(131072);
  unsigned short* w2T  = alloc(2048);
  (void)ws_size; (void)in_sizes; (void)n_in; (void)out_size;

  // K1: gather+cross -> high[:,128:256] + weight transposes
  prep_kernel<<<2353, 256, 0, stream>>>(ent_idx, head_tab, ent_tab,
      w_cf, w_fc, w_ef, w_fe, b_c, b_e, Wf, Wu, W0, W1, W2,
      high, wfT, wuT, w0T, w1T, w2T);
  // K2: cf chain -> high[:,0:128]
  cf_chain_kernel<<<512, 256, 0, stream>>>(features, wfT, wuT, bf_, bu, high);
  // K3: x0 = relu(high @ W0 + b0), 128x128 tiles
  gemm128_kernel<<<dim3(4, 128), 256, 0, stream>>>(high, w0T, b0, x0, 256, 512);
  // K4: x1 GEMM + W2 + softmax + target
  gemm_w1_final_kernel<<<512, 256, 0, stream>>>(x0, w1T, b1, w2T, b2, target, out);
}